// Round 1
// baseline (1138.097 us; speedup 1.0000x reference)
//
#include <hip/hip_runtime.h>
#include <cstdint>
#include <cstddef>

// ---------------- constants ----------------
static constexpr int F      = 6912;          // C*S*S
static constexpr int BATCH  = 64;
static constexpr size_t NF  = (size_t)BATCH * F;   // 442368 (== B*C*H*W too)
static constexpr int KSPLIT = 4;
static constexpr int KCH    = F / KSPLIT;    // 1728
static constexpr int BNT    = 64;            // n tile
static constexpr int BKT    = 64;            // k per LDS stage
static constexpr int NTILES = F / BNT;       // 108

typedef short bf16x8 __attribute__((ext_vector_type(8)));
typedef float f32x4  __attribute__((ext_vector_type(4)));

__device__ __forceinline__ unsigned short f2bf(float f) {
    union { float f; uint32_t u; } x; x.f = f;
    uint32_t r = x.u + 0x7fffu + ((x.u >> 16) & 1u);
    return (unsigned short)(r >> 16);
}

union PK16 { unsigned short u[16]; uint4 v[2]; };

// ---------------- build E = K - I (bf16) and E^T ----------------
__global__ __launch_bounds__(256) void build_e_et(const float* __restrict__ K,
                                                  unsigned short* __restrict__ E,
                                                  unsigned short* __restrict__ ET) {
    __shared__ float tile[64][65];
    int bi = blockIdx.x * 64, bj = blockIdx.y * 64;
    int t = threadIdx.x;
    int r = t >> 2, c0 = (t & 3) * 16;
    const float4* src = reinterpret_cast<const float4*>(K + (size_t)(bi + r) * F + bj + c0);
    float4 v0 = src[0], v1 = src[1], v2 = src[2], v3 = src[3];
    float vv[16] = {v0.x,v0.y,v0.z,v0.w, v1.x,v1.y,v1.z,v1.w,
                    v2.x,v2.y,v2.z,v2.w, v3.x,v3.y,v3.z,v3.w};
#pragma unroll
    for (int e = 0; e < 16; ++e) {
        float f = vv[e];
        if (bi + r == bj + c0 + e) f -= 1.0f;
        tile[r][c0 + e] = f;
    }
    __syncthreads();
    PK16 pk;
#pragma unroll
    for (int e = 0; e < 16; ++e) pk.u[e] = f2bf(tile[r][c0 + e]);
    uint4* d0 = reinterpret_cast<uint4*>(E + (size_t)(bi + r) * F + bj + c0);
    d0[0] = pk.v[0]; d0[1] = pk.v[1];
#pragma unroll
    for (int e = 0; e < 16; ++e) pk.u[e] = f2bf(tile[c0 + e][r]);
    uint4* d1 = reinterpret_cast<uint4*>(ET + (size_t)(bj + r) * F + bi + c0);
    d1[0] = pk.v[0]; d1[1] = pk.v[1];
}

// ---------------- skinny GEMM: out[b][n] (+)= sum_k A[b][k] * Brow[n][k] ----------------
// MODE 0: write partial slices part[kc][b][n]   MODE 1: atomicAdd scale*acc into outp[b][n]
template<int MODE>
__global__ __launch_bounds__(256) void gemm_skinny(
    const float*          __restrict__ A,     // [64][F] f32 (converted to bf16 on the fly)
    const unsigned short* __restrict__ Brow,  // [F][F] bf16, row n contiguous in k
    float*                __restrict__ outp,
    float scale)
{
    __shared__ __align__(16) unsigned short As[64][72];
    __shared__ __align__(16) unsigned short Bs[64][72];
    int nt = blockIdx.x, kc = blockIdx.y;
    int n0 = nt * BNT;
    int t = threadIdx.x;
    int w = t >> 6, l = t & 63;
    int srow = t >> 2, sc0 = (t & 3) * 16;
    const int lrow = l & 15, lk = (l >> 4) * 8;

    f32x4 acc[4];
#pragma unroll
    for (int i = 0; i < 4; ++i) acc[i] = (f32x4)0.0f;

    for (int s = 0; s < KCH / BKT; ++s) {
        int kb = kc * KCH + s * BKT;
        const float4* ap = reinterpret_cast<const float4*>(A + (size_t)srow * F + kb + sc0);
        float4 a0 = ap[0], a1 = ap[1], a2 = ap[2], a3 = ap[3];
        const uint4* bp = reinterpret_cast<const uint4*>(Brow + (size_t)(n0 + srow) * F + kb + sc0);
        uint4 b0 = bp[0], b1 = bp[1];
        float av[16] = {a0.x,a0.y,a0.z,a0.w, a1.x,a1.y,a1.z,a1.w,
                        a2.x,a2.y,a2.z,a2.w, a3.x,a3.y,a3.z,a3.w};
        PK16 apk;
#pragma unroll
        for (int e = 0; e < 16; ++e) apk.u[e] = f2bf(av[e]);
        __syncthreads();   // protect previous stage's reads
        *reinterpret_cast<uint4*>(&As[srow][sc0])     = apk.v[0];
        *reinterpret_cast<uint4*>(&As[srow][sc0 + 8]) = apk.v[1];
        *reinterpret_cast<uint4*>(&Bs[srow][sc0])     = b0;
        *reinterpret_cast<uint4*>(&Bs[srow][sc0 + 8]) = b1;
        __syncthreads();
#pragma unroll
        for (int ks = 0; ks < BKT / 32; ++ks) {
            bf16x8 af = *reinterpret_cast<const bf16x8*>(&As[w * 16 + lrow][ks * 32 + lk]);
#pragma unroll
            for (int j = 0; j < 4; ++j) {
                bf16x8 bf = *reinterpret_cast<const bf16x8*>(&Bs[j * 16 + lrow][ks * 32 + lk]);
                acc[j] = __builtin_amdgcn_mfma_f32_16x16x32_bf16(af, bf, acc[j], 0, 0, 0);
            }
        }
    }
    int col = l & 15, rb = (l >> 4) * 4;
#pragma unroll
    for (int j = 0; j < 4; ++j) {
        int n = n0 + j * 16 + col;
#pragma unroll
        for (int r = 0; r < 4; ++r) {
            int m = w * 16 + rb + r;
            if (MODE == 0) outp[((size_t)kc * BATCH + m) * F + n] = acc[j][r];
            else atomicAdd(outp + (size_t)m * F + n, scale * acc[j][r]);
        }
    }
}

// ---------------- BN(batch) + ReLU + base update ----------------
// KY[b][i] = A1[b][i] + sum_kc part[kc][b][i]; stats over b; s = relu(BN(KY));
// s_out = s ; Onew[b][i] = Obase[b][i] + scale*s
__global__ __launch_bounds__(256) void bn_relu_step(
    const float* __restrict__ part, const float* __restrict__ A1,
    const float* __restrict__ Obase,
    const float* __restrict__ gamma, const float* __restrict__ beta,
    float scale,
    float* __restrict__ s_out, float* __restrict__ Onew)
{
    int fl = threadIdx.x & 63;
    int q  = threadIdx.x >> 6;              // wave id -> batch quarter
    int i  = blockIdx.x * 64 + fl;
    float sum = 0.f, sq = 0.f;
    for (int b = q * 16; b < q * 16 + 16; ++b) {
        size_t o = (size_t)b * F + i;
        float v = A1[o] + part[o] + part[NF + o] + part[2 * NF + o] + part[3 * NF + o];
        sum += v; sq += v * v;
    }
    __shared__ float rs[4][64], rq[4][64];
    rs[q][fl] = sum; rq[q][fl] = sq;
    __syncthreads();
    float ts = rs[0][fl] + rs[1][fl] + rs[2][fl] + rs[3][fl];
    float tq = rq[0][fl] + rq[1][fl] + rq[2][fl] + rq[3][fl];
    float mean = ts * (1.f / BATCH);
    float var  = tq * (1.f / BATCH) - mean * mean;
    float inv  = rsqrtf(var + 1e-5f) * gamma[i];
    float sh   = beta[i];
    for (int b = q * 16; b < q * 16 + 16; ++b) {
        size_t o = (size_t)b * F + i;
        float v = A1[o] + part[o] + part[NF + o] + part[2 * NF + o] + part[3 * NF + o];
        float kyn = (v - mean) * inv + sh;
        float sv = fmaxf(kyn, 0.f);
        s_out[o] = sv;
        Onew[o] = Obase[o] + scale * sv;
    }
}

// ---------------- diffusion (ADI, Thomas) ----------------
__global__ __launch_bounds__(192) void diffusion_kern(
    const float* __restrict__ x,
    const float* __restrict__ ab1, const float* __restrict__ bb1,
    const float* __restrict__ atc1, const float* __restrict__ btc1,
    const float* __restrict__ mix1,
    const float* __restrict__ ab2, const float* __restrict__ bb2,
    const float* __restrict__ atc2, const float* __restrict__ btc2,
    const float* __restrict__ mix2,
    float* __restrict__ out1, float* __restrict__ out2)
{
    int blk = blockIdx.x;
    bool second = blk >= 64;
    int b = blk & 63;
    const float* ab  = second ? ab2  : ab1;
    const float* bb  = second ? bb2  : bb1;
    const float* atc = second ? atc2 : atc1;
    const float* btc = second ? btc2 : btc1;
    const float* mx  = second ? mix2 : mix1;
    float dt = second ? 0.002f : 0.001f;
    int nsteps = second ? 5 : 8;
    float* out = second ? out2 : out1;

    __shared__ float u[3][48][49];
    __shared__ float cs[144][49];
    int t = threadIdx.x;
    for (int idx = t; idx < 6912; idx += 192) {
        int c = idx / 2304, rem = idx % 2304;
        u[c][rem / 48][rem % 48] = x[(size_t)b * 6912 + idx];
    }
    float m00 = mx[0], m01 = mx[1], m02 = mx[2];
    float m10 = mx[3], m11 = mx[4], m12 = mx[5];
    float m20 = mx[6], m21 = mx[7], m22 = mx[8];
    __syncthreads();
    float tcur = 0.f;
    float dt2 = dt * 0.5f;
    for (int step = 0; step < nsteps; ++step) {
        // mix (per-pixel 3x3)
        float v0[12], v1[12], v2[12];
#pragma unroll
        for (int j = 0; j < 12; ++j) {
            int p = t + j * 192;
            int h = p / 48, wq = p % 48;
            v0[j] = u[0][h][wq]; v1[j] = u[1][h][wq]; v2[j] = u[2][h][wq];
        }
        __syncthreads();
#pragma unroll
        for (int j = 0; j < 12; ++j) {
            int p = t + j * 192;
            int h = p / 48, wq = p % 48;
            u[0][h][wq] = m00 * v0[j] + m01 * v1[j] + m02 * v2[j];
            u[1][h][wq] = m10 * v0[j] + m11 * v1[j] + m12 * v2[j];
            u[2][h][wq] = m20 * v0[j] + m21 * v1[j] + m22 * v2[j];
        }
        __syncthreads();
        // Thomas along W
        if (t < 144) {
            int c = t / 48, h = t % 48;
            const float* abp = ab + c * 2304 + h * 48;
            const float* atp = atc + c * 2304 + h * 48;
            float cp = 0.f, dp = 0.f;
            for (int k = 0; k < 48; ++k) {
                float co = fminf(fmaxf(abp[k] + atp[k] * tcur, 1e-6f), 10.f) * dt2;
                float bd = ((k == 0) || (k == 47)) ? (1.f + co) : (1.f + 2.f * co);
                float den = bd + co * cp + 1e-6f;   // b - a*cp + EPS, a = -co
                float rin = 1.f / den;
                float csv = -co * rin;
                float dsv = (u[c][h][k] + co * dp) * rin;
                cs[t][k] = csv; u[c][h][k] = dsv;
                cp = csv; dp = dsv;
            }
            float xv = dp;
            u[c][h][47] = xv;
            for (int k = 46; k >= 0; --k) { xv = u[c][h][k] - cs[t][k] * xv; u[c][h][k] = xv; }
        }
        __syncthreads();
        tcur += dt2;
        // Thomas along H
        if (t < 144) {
            int c = t / 48, wq = t % 48;
            const float* bbp = bb + c * 2304 + wq;
            const float* btp = btc + c * 2304 + wq;
            float cp = 0.f, dp = 0.f;
            for (int k = 0; k < 48; ++k) {
                float co = fminf(fmaxf(bbp[k * 48] + btp[k * 48] * tcur, 1e-6f), 10.f) * dt2;
                float bd = ((k == 0) || (k == 47)) ? (1.f + co) : (1.f + 2.f * co);
                float den = bd + co * cp + 1e-6f;
                float rin = 1.f / den;
                float csv = -co * rin;
                float dsv = (u[c][k][wq] + co * dp) * rin;
                cs[t][k] = csv; u[c][k][wq] = dsv;
                cp = csv; dp = dsv;
            }
            float xv = dp;
            u[c][47][wq] = xv;
            for (int k = 46; k >= 0; --k) { xv = u[c][k][wq] - cs[t][k] * xv; u[c][k][wq] = xv; }
        }
        __syncthreads();
        tcur += dt2;
    }
    for (int idx = t; idx < 6912; idx += 192) {
        int c = idx / 2304, rem = idx % 2304;
        out[(size_t)b * 6912 + idx] = u[c][rem / 48][rem % 48];
    }
}

// ---------------- combine + final per-channel BN ----------------
__global__ __launch_bounds__(256) void combine_pass1(
    const float* __restrict__ cw,
    const float* __restrict__ d1, const float* __restrict__ d2,
    const float* __restrict__ yp, const float* __restrict__ yh,
    float* __restrict__ comb, float* __restrict__ stats)
{
    float c0 = cw[0], c1 = cw[1], c2 = cw[2], c3 = cw[3];
    float mxv = fmaxf(fmaxf(c0, c1), fmaxf(c2, c3));
    float e0 = expf(c0 - mxv), e1 = expf(c1 - mxv), e2 = expf(c2 - mxv), e3 = expf(c3 - mxv);
    float es = e0 + e1 + e2 + e3;
    float w0 = e0 / es, w1 = e1 / es, w2 = e2 / es, w3 = e3 / es;
    size_t base = (size_t)blockIdx.x * 1024;
    float ls[3] = {0.f, 0.f, 0.f}, lq[3] = {0.f, 0.f, 0.f};
#pragma unroll
    for (int j = 0; j < 4; ++j) {
        size_t idx = base + threadIdx.x + j * 256;
        float v = w0 * d1[idx] + w1 * d2[idx] + w2 * yp[idx] + w3 * yh[idx];
        comb[idx] = v;
        int c = (int)((idx / 2304) % 3);
        if (c == 0)      { ls[0] += v; lq[0] += v * v; }
        else if (c == 1) { ls[1] += v; lq[1] += v * v; }
        else             { ls[2] += v; lq[2] += v * v; }
    }
    __shared__ float bsum[6];
    if (threadIdx.x < 6) bsum[threadIdx.x] = 0.f;
    __syncthreads();
#pragma unroll
    for (int c = 0; c < 3; ++c) {
        atomicAdd(&bsum[c], ls[c]);
        atomicAdd(&bsum[3 + c], lq[c]);
    }
    __syncthreads();
    if (threadIdx.x < 6) atomicAdd(&stats[threadIdx.x], bsum[threadIdx.x]);
}

__global__ __launch_bounds__(256) void combine_pass2(
    const float* __restrict__ comb, const float* __restrict__ stats,
    const float* __restrict__ fng, const float* __restrict__ fnb,
    float* __restrict__ out0)
{
    const float inv_n = 1.f / 147456.f;   // 64*48*48
    size_t base = (size_t)blockIdx.x * 1024;
#pragma unroll
    for (int j = 0; j < 4; ++j) {
        size_t idx = base + threadIdx.x + j * 256;
        int c = (int)((idx / 2304) % 3);
        float mean = stats[c] * inv_n;
        float var = stats[3 + c] * inv_n - mean * mean;
        out0[idx] = (comb[idx] - mean) * rsqrtf(var + 1e-5f) * fng[c] + fnb[c];
    }
}

// ---------------- workspace ----------------
static constexpr size_t EB = (size_t)F * F * 2;              // one bf16 matrix
static constexpr size_t NF4 = NF * 4;                        // one activation buffer (f32)
static constexpr size_t WS_NEED = 6 * EB + 4 * NF4 /*part*/ + NF4 /*s*/ +
                                  8 * NF4 /*Y1..3,Yh1..2,Z0..2*/ + NF4 /*comb*/ + 4096;

static void* g_ws = nullptr;
namespace {
struct WsInit {
    WsInit() { if (hipMalloc(&g_ws, WS_NEED) != hipSuccess) g_ws = nullptr; }
};
WsInit g_wsinit;
}

// ---------------- launch ----------------
extern "C" void kernel_launch(void* const* d_in, const int* in_sizes, int n_in,
                              void* d_out, int out_size, void* d_ws, size_t ws_size,
                              hipStream_t stream)
{
    const float* x    = (const float*)d_in[0];
    const float* ab1  = (const float*)d_in[1];
    const float* bb1  = (const float*)d_in[2];
    const float* atc1 = (const float*)d_in[3];
    const float* btc1 = (const float*)d_in[4];
    const float* mix1 = (const float*)d_in[5];
    const float* ab2  = (const float*)d_in[6];
    const float* bb2  = (const float*)d_in[7];
    const float* atc2 = (const float*)d_in[8];
    const float* btc2 = (const float*)d_in[9];
    const float* mix2 = (const float*)d_in[10];
    const float* Kp   = (const float*)d_in[11];
    const float* gp   = (const float*)d_in[12];
    const float* bp   = (const float*)d_in[13];
    const float* Ky   = (const float*)d_in[14];
    const float* gy   = (const float*)d_in[15];
    const float* by_  = (const float*)d_in[16];
    const float* Kz   = (const float*)d_in[17];
    const float* gz   = (const float*)d_in[18];
    const float* bz   = (const float*)d_in[19];
    const float* cw   = (const float*)d_in[20];
    const float* fng  = (const float*)d_in[21];
    const float* fnb  = (const float*)d_in[22];

    float* out   = (float*)d_out;
    float* o_cmb = out;
    float* o_d1  = out + NF;
    float* o_d2  = out + 2 * NF;
    float* o_yp  = out + 3 * NF;
    float* o_yh  = out + 4 * NF;

    char* wsb = (ws_size >= WS_NEED) ? (char*)d_ws : (char*)g_ws;
    if (!wsb) wsb = (char*)d_ws;   // last resort

    char* p = wsb;
    auto bump = [&](size_t bytes) { char* r = p; p += (bytes + 255) & ~(size_t)255; return r; };
    unsigned short* Ep  = (unsigned short*)bump(EB);
    unsigned short* EpT = (unsigned short*)bump(EB);
    unsigned short* Ey  = (unsigned short*)bump(EB);
    unsigned short* EyT = (unsigned short*)bump(EB);
    unsigned short* Ez  = (unsigned short*)bump(EB);
    unsigned short* EzT = (unsigned short*)bump(EB);
    float* part = (float*)bump(4 * NF4);
    float* sbuf = (float*)bump(NF4);
    float* Y1   = (float*)bump(NF4);
    float* Y2   = (float*)bump(NF4);
    float* Y3   = (float*)bump(NF4);
    float* Yh1  = (float*)bump(NF4);
    float* Yh2  = (float*)bump(NF4);
    float* Z0   = (float*)bump(NF4);
    float* Z1   = (float*)bump(NF4);
    float* Z2   = (float*)bump(NF4);
    float* comb = (float*)bump(NF4);
    float* stats = (float*)bump(256);

    hipMemsetAsync(stats, 0, 32, stream);
    hipMemsetAsync(Z0, 0, NF4, stream);

    build_e_et<<<dim3(108, 108), 256, 0, stream>>>(Kp, Ep, EpT);
    build_e_et<<<dim3(108, 108), 256, 0, stream>>>(Ky, Ey, EyT);
    build_e_et<<<dim3(108, 108), 256, 0, stream>>>(Kz, Ez, EzT);

    diffusion_kern<<<128, 192, 0, stream>>>(x, ab1, bb1, atc1, btc1, mix1,
                                            ab2, bb2, atc2, btc2, mix2, o_d1, o_d2);

    auto sym = [&](const float* A, const float* Obase, float* Onew,
                   const unsigned short* E, const unsigned short* ET,
                   const float* g, const float* bt, float sc) {
        gemm_skinny<0><<<dim3(NTILES, KSPLIT), 256, 0, stream>>>(A, E, part, 0.f);
        bn_relu_step<<<F / 64, 256, 0, stream>>>(part, A, Obase, g, bt, sc, sbuf, Onew);
        gemm_skinny<1><<<dim3(NTILES, KSPLIT), 256, 0, stream>>>(sbuf, ET, Onew, sc);
    };

    // Parabolic: Y <- Y + 0.5 * (-(s + s@E))
    sym(x,  x,  Y1,  Ep, EpT, gp, bp, -0.5f);
    sym(Y1, Y1, Y2,  Ep, EpT, gp, bp, -0.5f);
    sym(Y2, Y2, Y3,  Ep, EpT, gp, bp, -0.5f);
    sym(Y3, Y3, o_yp, Ep, EpT, gp, bp, -0.5f);

    // Hamiltonian: Yh += 0.8*(s_z + s_z@Ey) ; Zh += 0.8*(s_y + s_y@Ez); last Zh unused
    sym(Z0,  x,   Yh1,  Ey, EyT, gy, by_, 0.8f);
    sym(Yh1, Z0,  Z1,   Ez, EzT, gz, bz,  0.8f);
    sym(Z1,  Yh1, Yh2,  Ey, EyT, gy, by_, 0.8f);
    sym(Yh2, Z1,  Z2,   Ez, EzT, gz, bz,  0.8f);
    sym(Z2,  Yh2, o_yh, Ey, EyT, gy, by_, 0.8f);

    combine_pass1<<<432, 256, 0, stream>>>(cw, o_d1, o_d2, o_yp, o_yh, comb, stats);
    combine_pass2<<<432, 256, 0, stream>>>(comb, stats, fng, fnb, o_cmb);
}

// Round 2
// 1088.439 us; speedup vs baseline: 1.0456x; 1.0456x over previous
//
#include <hip/hip_runtime.h>
#include <cstdint>
#include <cstddef>

// ---------------- constants ----------------
static constexpr int F      = 6912;          // C*S*S
static constexpr int BATCH  = 64;
static constexpr size_t NF  = (size_t)BATCH * F;   // 442368
static constexpr int BKT    = 64;            // k per LDS stage
static constexpr int NT     = F / BKT;       // 108 k-stages
static constexpr int NTILES = F / 64;        // 108 n-tiles

typedef short bf16x8 __attribute__((ext_vector_type(8)));
typedef float f32x4  __attribute__((ext_vector_type(4)));
typedef unsigned short ushort_t;

__device__ __forceinline__ unsigned short f2bf(float f) {
    union { float f; uint32_t u; } x; x.f = f;
    uint32_t r = x.u + 0x7fffu + ((x.u >> 16) & 1u);
    return (unsigned short)(r >> 16);
}

union PK16 { unsigned short u[16]; uint4 v[2]; };

#define GLOAD_LDS16(gp, lp) \
    __builtin_amdgcn_global_load_lds((const __attribute__((address_space(1))) void*)(gp), \
                                     (__attribute__((address_space(3))) void*)(lp), 16, 0, 0)

// ---------------- build E = K - I (bf16) and E^T, 3 matrices in one launch ----------------
__global__ __launch_bounds__(256) void build_e_et3(
    const float* __restrict__ K0, const float* __restrict__ K1, const float* __restrict__ K2,
    unsigned short* __restrict__ E0, unsigned short* __restrict__ ET0,
    unsigned short* __restrict__ E1, unsigned short* __restrict__ ET1,
    unsigned short* __restrict__ E2, unsigned short* __restrict__ ET2) {
    __shared__ float tile[64][65];
    int z = blockIdx.z;
    const float* K = (z == 0) ? K0 : (z == 1) ? K1 : K2;
    unsigned short* E  = (z == 0) ? E0  : (z == 1) ? E1  : E2;
    unsigned short* ET = (z == 0) ? ET0 : (z == 1) ? ET1 : ET2;
    int bi = blockIdx.x * 64, bj = blockIdx.y * 64;
    int t = threadIdx.x;
    int r = t >> 2, c0 = (t & 3) * 16;
    const float4* src = reinterpret_cast<const float4*>(K + (size_t)(bi + r) * F + bj + c0);
    float4 v0 = src[0], v1 = src[1], v2 = src[2], v3 = src[3];
    float vv[16] = {v0.x,v0.y,v0.z,v0.w, v1.x,v1.y,v1.z,v1.w,
                    v2.x,v2.y,v2.z,v2.w, v3.x,v3.y,v3.z,v3.w};
#pragma unroll
    for (int e = 0; e < 16; ++e) {
        float f = vv[e];
        if (bi + r == bj + c0 + e) f -= 1.0f;
        tile[r][c0 + e] = f;
    }
    __syncthreads();
    PK16 pk;
#pragma unroll
    for (int e = 0; e < 16; ++e) pk.u[e] = f2bf(tile[r][c0 + e]);
    uint4* d0 = reinterpret_cast<uint4*>(E + (size_t)(bi + r) * F + bj + c0);
    d0[0] = pk.v[0]; d0[1] = pk.v[1];
#pragma unroll
    for (int e = 0; e < 16; ++e) pk.u[e] = f2bf(tile[c0 + e][r]);
    uint4* d1 = reinterpret_cast<uint4*>(ET + (size_t)(bj + r) * F + bi + c0);
    d1[0] = pk.v[0]; d1[1] = pk.v[1];
}

// ---------------- fused skinny GEMM (M=64) ----------------
// Tile: 64 m x 64 n, full K per block. 4 waves. LDS: 8 double-buffers (A 8KB + B 8KB each),
// depth-3 prefetch via global_load_lds + counted vmcnt. XOR-swizzled (both-sides) layout.
// MODE 0: KY = base + A@B^T(rows) -> batch-BN -> relu -> write s_f32 + s_bf16
// MODE 1: Onew = base + scale*(s_in + A@B^T) -> write Onew f32 + bf16
__device__ __forceinline__ void issue_tile(const ushort_t* __restrict__ Abf,
                                           const ushort_t* __restrict__ Brow,
                                           ushort_t* buf, int n0, int t, int w, int l) {
    int k0 = t * BKT;
#pragma unroll
    for (int i = 0; i < 2; ++i) {
        int slotbase = w * 128 + i * 64;
        int slot = slotbase + l;
        int row = slot >> 3;
        int cs16 = (slot & 7) ^ (row & 7);
        const ushort_t* gp = Abf + (size_t)row * F + k0 + cs16 * 8;
        GLOAD_LDS16(gp, buf + slotbase * 8);
    }
#pragma unroll
    for (int i = 0; i < 2; ++i) {
        int slotbase = w * 128 + i * 64;
        int slot = slotbase + l;
        int row = slot >> 3;
        int cs16 = (slot & 7) ^ (row & 7);
        const ushort_t* gp = Brow + (size_t)(n0 + row) * F + k0 + cs16 * 8;
        GLOAD_LDS16(gp, buf + 4096 + slotbase * 8);
    }
}

__device__ __forceinline__ void compute_tile(const ushort_t* buf, f32x4 acc[4], int w, int l) {
    int lrow = l & 15, lq = l >> 4;
    int arow = w * 16 + lrow;
    const char* base = (const char*)buf;
#pragma unroll
    for (int ks = 0; ks < 2; ++ks) {
        int acol = ((ks * 4 + lq) ^ (arow & 7)) * 16;
        bf16x8 af = *(const bf16x8*)(base + arow * 128 + acol);
#pragma unroll
        for (int j = 0; j < 4; ++j) {
            int brow = j * 16 + lrow;
            int bcol = ((ks * 4 + lq) ^ (brow & 7)) * 16;
            bf16x8 bf = *(const bf16x8*)(base + 8192 + brow * 128 + bcol);
            acc[j] = __builtin_amdgcn_mfma_f32_16x16x32_bf16(af, bf, acc[j], 0, 0, 0);
        }
    }
}

template<int MODE>
__global__ __launch_bounds__(256) void gemm_fused(
    const ushort_t* __restrict__ Abf, const ushort_t* __restrict__ Brow,
    const float* __restrict__ base_f32,   // MODE0: A1 (identity term); MODE1: Obase
    const float* __restrict__ s_in,       // MODE1 only
    const float* __restrict__ gamma, const float* __restrict__ beta,
    float scale,
    float* __restrict__ out_f32, ushort_t* __restrict__ out_bf)
{
    extern __shared__ char smem[];            // 8 * 16384 = 131072 bytes staging
    ushort_t* stage = (ushort_t*)smem;
    __shared__ float redS[256], redQ[256];

    int n0 = blockIdx.x * 64;
    int tid = threadIdx.x;
    int w = tid >> 6, l = tid & 63;

    f32x4 acc[4];
#pragma unroll
    for (int j = 0; j < 4; ++j) acc[j] = (f32x4)0.0f;

    issue_tile(Abf, Brow, stage + 0 * 8192, n0, 0, w, l);
    issue_tile(Abf, Brow, stage + 1 * 8192, n0, 1, w, l);
    issue_tile(Abf, Brow, stage + 2 * 8192, n0, 2, w, l);

    for (int t = 0; t < NT; ++t) {
        bool more = (t + 3 < NT);
        if (more) issue_tile(Abf, Brow, stage + ((t + 3) & 7) * 8192, n0, t + 3, w, l);
        int ahead = more ? 3 : (NT - 1 - t);
        if (ahead >= 3)      asm volatile("s_waitcnt vmcnt(12)" ::: "memory");
        else if (ahead == 2) asm volatile("s_waitcnt vmcnt(8)"  ::: "memory");
        else if (ahead == 1) asm volatile("s_waitcnt vmcnt(4)"  ::: "memory");
        else                 asm volatile("s_waitcnt vmcnt(0)"  ::: "memory");
        __builtin_amdgcn_s_barrier();
        asm volatile("" ::: "memory");
        compute_tile(stage + (t & 7) * 8192, acc, w, l);
    }

    int lrow = l & 15, lq = l >> 4;
    if (MODE == 0) {
        float v[4][4];
#pragma unroll
        for (int j = 0; j < 4; ++j)
#pragma unroll
            for (int r = 0; r < 4; ++r) {
                int m = w * 16 + lq * 4 + r;
                int n = n0 + j * 16 + lrow;
                v[j][r] = acc[j][r] + base_f32[(size_t)m * F + n];
            }
#pragma unroll
        for (int j = 0; j < 4; ++j) {
            float ps = v[j][0] + v[j][1] + v[j][2] + v[j][3];
            float pq = v[j][0]*v[j][0] + v[j][1]*v[j][1] + v[j][2]*v[j][2] + v[j][3]*v[j][3];
            ps += __shfl_xor(ps, 16); pq += __shfl_xor(pq, 16);
            ps += __shfl_xor(ps, 32); pq += __shfl_xor(pq, 32);
            if (lq == 0) { redS[(w * 4 + j) * 16 + lrow] = ps; redQ[(w * 4 + j) * 16 + lrow] = pq; }
        }
        __syncthreads();
#pragma unroll
        for (int j = 0; j < 4; ++j) {
            float ts = redS[(0*4+j)*16+lrow] + redS[(1*4+j)*16+lrow] + redS[(2*4+j)*16+lrow] + redS[(3*4+j)*16+lrow];
            float tq = redQ[(0*4+j)*16+lrow] + redQ[(1*4+j)*16+lrow] + redQ[(2*4+j)*16+lrow] + redQ[(3*4+j)*16+lrow];
            float mn = ts * (1.f / 64.f);
            float vr = tq * (1.f / 64.f) - mn * mn;
            int n = n0 + j * 16 + lrow;
            float inv = rsqrtf(vr + 1e-5f) * gamma[n];
            float bet = beta[n];
#pragma unroll
            for (int r = 0; r < 4; ++r) {
                int m = w * 16 + lq * 4 + r;
                float sv = fmaxf((v[j][r] - mn) * inv + bet, 0.f);
                out_f32[(size_t)m * F + n] = sv;
                out_bf[(size_t)m * F + n] = f2bf(sv);
            }
        }
    } else {
#pragma unroll
        for (int j = 0; j < 4; ++j)
#pragma unroll
            for (int r = 0; r < 4; ++r) {
                int m = w * 16 + lq * 4 + r;
                int n = n0 + j * 16 + lrow;
                size_t o = (size_t)m * F + n;
                float ov = base_f32[o] + scale * (s_in[o] + acc[j][r]);
                out_f32[o] = ov;
                out_bf[o] = f2bf(ov);
            }
    }
}

// ---------------- f32 -> bf16 convert ----------------
__global__ __launch_bounds__(256) void cvt_bf(const float* __restrict__ in, ushort_t* __restrict__ out) {
    size_t i = ((size_t)blockIdx.x * 256 + threadIdx.x) * 4;
    float4 v = *reinterpret_cast<const float4*>(in + i);
    ushort_t p[4] = { f2bf(v.x), f2bf(v.y), f2bf(v.z), f2bf(v.w) };
    *reinterpret_cast<uint2*>(out + i) = *reinterpret_cast<uint2*>(p);
}

// ---------------- coefficient transpose for H-solve ----------------
__global__ __launch_bounds__(256) void transpose_coeff(
    const float* __restrict__ b1, const float* __restrict__ t1,
    const float* __restrict__ b2, const float* __restrict__ t2,
    float* __restrict__ o) {
    int idx = blockIdx.x * 256 + threadIdx.x;
    if (idx >= 4 * 6912) return;
    int a = idx / 6912, rem = idx % 6912;
    int c = rem / 2304, r2 = rem % 2304, wq = r2 / 48, k = r2 % 48;
    const float* src = (a == 0) ? b1 : (a == 1) ? t1 : (a == 2) ? b2 : t2;
    o[idx] = src[c * 2304 + k * 48 + wq];
}

// ---------------- diffusion (ADI, register-resident Thomas) ----------------
__device__ __forceinline__ void thomas_row(float* up, int stride,
                                           const float* __restrict__ cb,
                                           const float* __restrict__ ct,
                                           float tcur, float dt2) {
    float cov[48], ur[48];
#pragma unroll
    for (int k = 0; k < 48; ++k)
        cov[k] = fminf(fmaxf(cb[k] + ct[k] * tcur, 1e-6f), 10.f) * dt2;
#pragma unroll
    for (int k = 0; k < 48; ++k) ur[k] = up[k * stride];
    float cp = 0.f, dp = 0.f;
#pragma unroll
    for (int k = 0; k < 48; ++k) {
        float co = cov[k];
        float bd = (k == 0 || k == 47) ? (1.f + co) : (1.f + 2.f * co);
        float den = bd + co * cp + 1e-6f;
        float rin = __builtin_amdgcn_rcpf(den);
        float cs = -co * rin;
        float ds = (ur[k] + co * dp) * rin;
        cov[k] = cs; ur[k] = ds; cp = cs; dp = ds;
    }
    float xv = ur[47];
#pragma unroll
    for (int k = 46; k >= 0; --k) { xv = ur[k] - cov[k] * xv; ur[k] = xv; }
#pragma unroll
    for (int k = 0; k < 48; ++k) up[k * stride] = ur[k];
}

__global__ __launch_bounds__(192) void diffusion_kern(
    const float* __restrict__ x,
    const float* __restrict__ ab1, const float* __restrict__ atc1,
    const float* __restrict__ ab2, const float* __restrict__ atc2,
    const float* __restrict__ btr,      // [bbT1, btcT1, bbT2, btcT2] each [3][48][48]
    const float* __restrict__ mix1, const float* __restrict__ mix2,
    float* __restrict__ out1, float* __restrict__ out2)
{
    int blk = blockIdx.x;
    bool second = blk >= 64;
    int b = blk & 63;
    const float* ab  = second ? ab2  : ab1;
    const float* atc = second ? atc2 : atc1;
    const float* bbT = btr + (second ? 13824 : 0);
    const float* btT = btr + (second ? 20736 : 6912);
    const float* mx  = second ? mix2 : mix1;
    float dt = second ? 0.002f : 0.001f;
    int nsteps = second ? 5 : 8;
    float* out = second ? out2 : out1;

    __shared__ float u[3][48][49];
    int t = threadIdx.x;
    for (int idx = t; idx < 6912; idx += 192) {
        int c = idx / 2304, rem = idx % 2304;
        u[c][rem / 48][rem % 48] = x[(size_t)b * 6912 + idx];
    }
    float m00 = mx[0], m01 = mx[1], m02 = mx[2];
    float m10 = mx[3], m11 = mx[4], m12 = mx[5];
    float m20 = mx[6], m21 = mx[7], m22 = mx[8];
    __syncthreads();
    float tcur = 0.f, dt2 = dt * 0.5f;
    int cc = t / 48, rc = t % 48;
    for (int step = 0; step < nsteps; ++step) {
        float v0[12], v1[12], v2[12];
#pragma unroll
        for (int j = 0; j < 12; ++j) {
            int p = t + j * 192;
            int h = p / 48, wq = p % 48;
            v0[j] = u[0][h][wq]; v1[j] = u[1][h][wq]; v2[j] = u[2][h][wq];
        }
        __syncthreads();
#pragma unroll
        for (int j = 0; j < 12; ++j) {
            int p = t + j * 192;
            int h = p / 48, wq = p % 48;
            u[0][h][wq] = m00 * v0[j] + m01 * v1[j] + m02 * v2[j];
            u[1][h][wq] = m10 * v0[j] + m11 * v1[j] + m12 * v2[j];
            u[2][h][wq] = m20 * v0[j] + m21 * v1[j] + m22 * v2[j];
        }
        __syncthreads();
        if (t < 144)
            thomas_row(&u[cc][rc][0], 1, ab + (cc * 48 + rc) * 48, atc + (cc * 48 + rc) * 48, tcur, dt2);
        __syncthreads();
        tcur += dt2;
        if (t < 144)
            thomas_row(&u[cc][0][rc], 49, bbT + (cc * 48 + rc) * 48, btT + (cc * 48 + rc) * 48, tcur, dt2);
        __syncthreads();
        tcur += dt2;
    }
    for (int idx = t; idx < 6912; idx += 192) {
        int c = idx / 2304, rem = idx % 2304;
        out[(size_t)b * 6912 + idx] = u[c][rem / 48][rem % 48];
    }
}

// ---------------- combine + final per-channel BN ----------------
__global__ __launch_bounds__(256) void combine_pass1(
    const float* __restrict__ cw,
    const float* __restrict__ d1, const float* __restrict__ d2,
    const float* __restrict__ yp, const float* __restrict__ yh,
    float* __restrict__ comb, float* __restrict__ stats)
{
    float c0 = cw[0], c1 = cw[1], c2 = cw[2], c3 = cw[3];
    float mxv = fmaxf(fmaxf(c0, c1), fmaxf(c2, c3));
    float e0 = expf(c0 - mxv), e1 = expf(c1 - mxv), e2 = expf(c2 - mxv), e3 = expf(c3 - mxv);
    float es = e0 + e1 + e2 + e3;
    float w0 = e0 / es, w1 = e1 / es, w2 = e2 / es, w3 = e3 / es;
    size_t base = (size_t)blockIdx.x * 1024;
    float ls[3] = {0.f, 0.f, 0.f}, lq[3] = {0.f, 0.f, 0.f};
#pragma unroll
    for (int j = 0; j < 4; ++j) {
        size_t idx = base + threadIdx.x + j * 256;
        float v = w0 * d1[idx] + w1 * d2[idx] + w2 * yp[idx] + w3 * yh[idx];
        comb[idx] = v;
        int c = (int)((idx / 2304) % 3);
        if (c == 0)      { ls[0] += v; lq[0] += v * v; }
        else if (c == 1) { ls[1] += v; lq[1] += v * v; }
        else             { ls[2] += v; lq[2] += v * v; }
    }
    __shared__ float bsum[6];
    if (threadIdx.x < 6) bsum[threadIdx.x] = 0.f;
    __syncthreads();
#pragma unroll
    for (int c = 0; c < 3; ++c) {
        atomicAdd(&bsum[c], ls[c]);
        atomicAdd(&bsum[3 + c], lq[c]);
    }
    __syncthreads();
    if (threadIdx.x < 6) atomicAdd(&stats[threadIdx.x], bsum[threadIdx.x]);
}

__global__ __launch_bounds__(256) void combine_pass2(
    const float* __restrict__ comb, const float* __restrict__ stats,
    const float* __restrict__ fng, const float* __restrict__ fnb,
    float* __restrict__ out0)
{
    const float inv_n = 1.f / 147456.f;
    size_t base = (size_t)blockIdx.x * 1024;
#pragma unroll
    for (int j = 0; j < 4; ++j) {
        size_t idx = base + threadIdx.x + j * 256;
        int c = (int)((idx / 2304) % 3);
        float mean = stats[c] * inv_n;
        float var = stats[3 + c] * inv_n - mean * mean;
        out0[idx] = (comb[idx] - mean) * rsqrtf(var + 1e-5f) * fng[c] + fnb[c];
    }
}

// ---------------- workspace ----------------
static constexpr size_t EB  = (size_t)F * F * 2;   // one bf16 matrix
static constexpr size_t NF4 = NF * 4;              // one f32 activation buffer
static constexpr size_t WS_NEED = 6 * EB + 12 * NF4 + 2 * (NF4 / 4) + (1 << 20);

static void* g_ws = nullptr;
namespace {
struct WsInit {
    WsInit() { if (hipMalloc(&g_ws, WS_NEED) != hipSuccess) g_ws = nullptr; }
};
WsInit g_wsinit;
}

// ---------------- launch ----------------
extern "C" void kernel_launch(void* const* d_in, const int* in_sizes, int n_in,
                              void* d_out, int out_size, void* d_ws, size_t ws_size,
                              hipStream_t stream)
{
    const float* x    = (const float*)d_in[0];
    const float* ab1  = (const float*)d_in[1];
    const float* bb1  = (const float*)d_in[2];
    const float* atc1 = (const float*)d_in[3];
    const float* btc1 = (const float*)d_in[4];
    const float* mix1 = (const float*)d_in[5];
    const float* ab2  = (const float*)d_in[6];
    const float* bb2  = (const float*)d_in[7];
    const float* atc2 = (const float*)d_in[8];
    const float* btc2 = (const float*)d_in[9];
    const float* mix2 = (const float*)d_in[10];
    const float* Kp   = (const float*)d_in[11];
    const float* gp   = (const float*)d_in[12];
    const float* bp   = (const float*)d_in[13];
    const float* Ky   = (const float*)d_in[14];
    const float* gy   = (const float*)d_in[15];
    const float* by_  = (const float*)d_in[16];
    const float* Kz   = (const float*)d_in[17];
    const float* gz   = (const float*)d_in[18];
    const float* bz   = (const float*)d_in[19];
    const float* cw   = (const float*)d_in[20];
    const float* fng  = (const float*)d_in[21];
    const float* fnb  = (const float*)d_in[22];

    float* out   = (float*)d_out;
    float* o_cmb = out;
    float* o_d1  = out + NF;
    float* o_d2  = out + 2 * NF;
    float* o_yp  = out + 3 * NF;
    float* o_yh  = out + 4 * NF;

    char* wsb = (ws_size >= WS_NEED) ? (char*)d_ws : (char*)g_ws;
    if (!wsb) wsb = (char*)d_ws;

    char* p = wsb;
    auto bump = [&](size_t bytes) { char* r = p; p += (bytes + 255) & ~(size_t)255; return r; };
    ushort_t* Ep  = (ushort_t*)bump(EB);
    ushort_t* EpT = (ushort_t*)bump(EB);
    ushort_t* Ey  = (ushort_t*)bump(EB);
    ushort_t* EyT = (ushort_t*)bump(EB);
    ushort_t* Ez  = (ushort_t*)bump(EB);
    ushort_t* EzT = (ushort_t*)bump(EB);
    float* sbuf  = (float*)bump(NF4);
    ushort_t* s_bf = (ushort_t*)bump(NF4 / 4 * 2);
    ushort_t* Abf  = (ushort_t*)bump(NF4 / 4 * 2);
    float* Z0f  = (float*)bump(NF4);
    float* Y1   = (float*)bump(NF4);
    float* Y2   = (float*)bump(NF4);
    float* Y3   = (float*)bump(NF4);
    float* Yh1  = (float*)bump(NF4);
    float* Z1   = (float*)bump(NF4);
    float* Yh2  = (float*)bump(NF4);
    float* Z2   = (float*)bump(NF4);
    float* comb = (float*)bump(NF4);
    float* stats = (float*)bump(256);
    float* btr   = (float*)bump(4 * 6912 * 4);

    hipMemsetAsync(stats, 0, 32, stream);
    hipMemsetAsync(Z0f, 0, NF4, stream);

    transpose_coeff<<<108, 256, 0, stream>>>(bb1, btc1, bb2, btc2, btr);
    diffusion_kern<<<128, 192, 0, stream>>>(x, ab1, atc1, ab2, atc2, btr, mix1, mix2, o_d1, o_d2);

    build_e_et3<<<dim3(108, 108, 3), 256, 0, stream>>>(Kp, Ky, Kz, Ep, EpT, Ey, EyT, Ez, EzT);

    cvt_bf<<<432, 256, 0, stream>>>(x, Abf);

    const size_t SMEM = 131072;
    auto sym = [&](const float* A1, const ushort_t* E, const ushort_t* ET,
                   const float* g, const float* bt, const float* Obase,
                   float sc, float* Onew) {
        gemm_fused<0><<<NTILES, 256, SMEM, stream>>>(Abf, E, A1, nullptr, g, bt, 0.f, sbuf, s_bf);
        gemm_fused<1><<<NTILES, 256, SMEM, stream>>>(s_bf, ET, Obase, sbuf, nullptr, nullptr, sc, Onew, Abf);
    };

    // Parabolic: Y <- Y + 0.5 * (-(s + s@E))
    sym(x,  Ep, EpT, gp, bp, x,  -0.5f, Y1);
    sym(Y1, Ep, EpT, gp, bp, Y1, -0.5f, Y2);
    sym(Y2, Ep, EpT, gp, bp, Y2, -0.5f, Y3);
    sym(Y3, Ep, EpT, gp, bp, Y3, -0.5f, o_yp);

    // Hamiltonian
    hipMemsetAsync(Abf, 0, NF * 2, stream);     // A = Z0 = 0 (bf16)
    sym(Z0f, Ey, EyT, gy, by_, x,   0.8f, Yh1);
    sym(Yh1, Ez, EzT, gz, bz,  Z0f, 0.8f, Z1);
    sym(Z1,  Ey, EyT, gy, by_, Yh1, 0.8f, Yh2);
    sym(Yh2, Ez, EzT, gz, bz,  Z1,  0.8f, Z2);
    sym(Z2,  Ey, EyT, gy, by_, Yh2, 0.8f, o_yh);

    combine_pass1<<<432, 256, 0, stream>>>(cw, o_d1, o_d2, o_yp, o_yh, comb, stats);
    combine_pass2<<<432, 256, 0, stream>>>(comb, stats, fng, fnb, o_cmb);
}